// Round 5
// baseline (639.831 us; speedup 1.0000x reference)
//
#include <hip/hip_runtime.h>
#include <hip/hip_cooperative_groups.h>

namespace cg = cooperative_groups;

// LogSignature depth-4, C=16, B=64, L=256, fp32.
// out/batch: [lvl1(16) | lvl2(256) | lvl3(4096) | lvl4(65536)] = 69904
// ws (floats): dx1 [j][256][16] (time-major, step 255 zero);
//              dxt [j][16][256] (component-major streams);
//              sig [j][4368]
// Primary: one cooperative kernel (s4 in regs across 2 grid syncs, LDS 8.5 KB
// so coop capacity >= 1024 under the runtime's 64KB/CU occupancy model).
// Fallback (coop launch rejected): 3-kernel path with the same scan core.

#define NC 16
#define NB 64
#define NSTEP 255
#define NT 256
#define OUTB 69904
#define SIG123 4368
#define OFF_L2 16
#define OFF_L3 272
#define OFF_L4 4368

#define DXT_OFF (NB * NT * NC)            // 262144
#define SIG_OFF (DXT_OFF + NB * NC * NT)  // 524288

// 28 VALU ops/step: 16 s4 FMAs + 12-op replicated scalar chain.
#define CHEN_STEP(DXA, DXB, DXC, Q0, Q1, Q2, Q3)                               \
  do {                                                                         \
    const float Pd = (DXB) * s1a;                                              \
    const float Qd = (DXB) * (DXA);                                            \
    const float pre4 = fmaf(1.f / 6.f, Pd, fmaf(1.f / 24.f, Qd, 0.5f * s2ab)); \
    const float T = fmaf((DXC), pre4, s3);                                     \
    s4v[0] = fmaf((Q0).x, T, s4v[0]);   s4v[1] = fmaf((Q0).y, T, s4v[1]);      \
    s4v[2] = fmaf((Q0).z, T, s4v[2]);   s4v[3] = fmaf((Q0).w, T, s4v[3]);      \
    s4v[4] = fmaf((Q1).x, T, s4v[4]);   s4v[5] = fmaf((Q1).y, T, s4v[5]);      \
    s4v[6] = fmaf((Q1).z, T, s4v[6]);   s4v[7] = fmaf((Q1).w, T, s4v[7]);      \
    s4v[8] = fmaf((Q2).x, T, s4v[8]);   s4v[9] = fmaf((Q2).y, T, s4v[9]);      \
    s4v[10] = fmaf((Q2).z, T, s4v[10]); s4v[11] = fmaf((Q2).w, T, s4v[11]);    \
    s4v[12] = fmaf((Q3).x, T, s4v[12]); s4v[13] = fmaf((Q3).y, T, s4v[13]);    \
    s4v[14] = fmaf((Q3).z, T, s4v[14]); s4v[15] = fmaf((Q3).w, T, s4v[15]);    \
    const float U = fmaf(0.5f, Pd, fmaf(1.f / 6.f, Qd, s2ab));                 \
    s3 = fmaf((DXC), U, s3);                                                   \
    s2ab = fmaf(0.5f, Qd, s2ab + Pd);                                          \
    s1a += (DXA);                                                              \
  } while (0)

#define LOAD_ROWS(Q0, Q1, Q2, Q3, TT)                                 \
  do {                                                                \
    const float4* _rw = (const float4*)(row0 + (((TT)) & 255) * NC);  \
    Q0 = _rw[0]; Q1 = _rw[1]; Q2 = _rw[2]; Q3 = _rw[3];               \
  } while (0)

// Chen scan over 256 steps (step 255 zero). Rows double-buffered at
// distance 2; per-lane streams prefetched one 4-step iter ahead.
__device__ __forceinline__ void scan_core(const float* row0, const float4* ra4,
                                          const float4* rb4, const float4* rc4,
                                          float s4v[16], float& s3, float& s2ab,
                                          float& s1a) {
    float4 p00, p01, p02, p03, p10, p11, p12, p13;
    LOAD_ROWS(p00, p01, p02, p03, 0);
    LOAD_ROWS(p10, p11, p12, p13, 1);
    float4 va = ra4[0], vb = rb4[0], vc = rc4[0];

    for (int it = 0; it < 64; ++it) {
        const int nit = (it + 1) & 63;  // wrap: last prefetch valid mem, unused
        const float4 nva = ra4[nit];
        const float4 nvb = rb4[nit];
        const float4 nvc = rc4[nit];
        const int t = it * 4;
        CHEN_STEP(va.x, vb.x, vc.x, p00, p01, p02, p03);
        LOAD_ROWS(p00, p01, p02, p03, t + 2);
        CHEN_STEP(va.y, vb.y, vc.y, p10, p11, p12, p13);
        LOAD_ROWS(p10, p11, p12, p13, t + 3);
        CHEN_STEP(va.z, vb.z, vc.z, p00, p01, p02, p03);
        LOAD_ROWS(p00, p01, p02, p03, t + 4);
        CHEN_STEP(va.w, vb.w, vc.w, p10, p11, p12, p13);
        LOAD_ROWS(p10, p11, p12, p13, t + 5);
        va = nva; vb = nvb; vc = nvc;
    }
}

// Coalesced level-4 writeout via two-chunk LDS transpose (stride 17: 2-way
// bank aliasing only). ls must hold 2176 floats. v[] is the thread's 16 d's.
__device__ __forceinline__ void store_l4(float* o4, const float v[16],
                                         float* ls, int tid) {
#pragma unroll
    for (int r = 0; r < 2; ++r) {
        __syncthreads();
        if ((tid >> 7) == r) {
            const int row = tid & 127;
#pragma unroll
            for (int d = 0; d < 16; ++d) ls[row * 17 + d] = v[d];
        }
        __syncthreads();
#pragma unroll
        for (int k = 0; k < 8; ++k) {
            const int el = tid + k * 256;
            o4[r * 2048 + el] = ls[(el >> 4) * 17 + (el & 15)];
        }
    }
}

// ---------------- primary: fused cooperative kernel ----------------
__global__ __launch_bounds__(256, 4) void k_fused(const float* __restrict__ path,
                                                  float* __restrict__ out,
                                                  float* __restrict__ ws) {
    cg::grid_group grid = cg::this_grid();
    const int bid = blockIdx.x;
    const int j = bid >> 4;
    const int a = bid & 15;
    const int tid = threadIdx.x;
    const int b = tid >> 4;
    const int c = tid & 15;

    float* dx1 = ws;
    float* dxt = ws + DXT_OFF;
    float* sig = ws + SIG_OFF;

    __shared__ float ls[2176];  // 8704 B: phase A staging / phase C transpose

    // ---- phase A: dx for t in [16a, 16a+16) of batch j ----
    {
        const float* pj = path + (size_t)j * NT * NC;
        const int t = 16 * a + (tid >> 4);
        const int i = tid & 15;
        float v = 0.f;
        if (t < NSTEP) v = pj[(t + 1) * NC + i] - pj[t * NC + i];
        dx1[(size_t)j * NT * NC + 256 * a + tid] = v;
        ls[tid] = v;
        __syncthreads();
        const int i2 = tid >> 4;
        const int t2l = tid & 15;
        dxt[(size_t)j * NC * NT + i2 * NT + 16 * a + t2l] = ls[t2l * 16 + i2];
    }
    __threadfence();
    grid.sync();

    // ---- phase B: scan ----
    float s4v[16];
#pragma unroll
    for (int d = 0; d < 16; ++d) s4v[d] = 0.f;
    float s3 = 0.f, s2ab = 0.f, s1a = 0.f;

    const float* row0 = dx1 + (size_t)j * NT * NC;
    const float4* ra4 = (const float4*)(dxt + ((size_t)j * NC + a) * NT);
    const float4* rb4 = (const float4*)(dxt + ((size_t)j * NC + b) * NT);
    const float4* rc4 = (const float4*)(dxt + ((size_t)j * NC + c) * NT);
    scan_core(row0, ra4, rb4, rc4, s4v, s3, s2ab, s1a);

    float* sg = sig + (size_t)j * SIG123;
    sg[OFF_L3 + (a * 16 + b) * 16 + c] = s3;
    if (c == 0) sg[OFF_L2 + a * 16 + b] = s2ab;
    if (tid == 0) sg[a] = s1a;
    __threadfence();
    grid.sync();

    // ---- phase C: log correction + writeout (s4 still in regs) ----
    const float* s1p = sg;
    const float* s2p = sg + OFF_L2;
    const float* s3p = sg + OFF_L3;

    const float s1b = s1p[b], s1c = s1p[c];
    const float s2bc = s2p[b * 16 + c];

    const float A = -0.5f * s1a;
    const float Bv = fmaf((1.f / 3.f) * s1a, s1b, -0.5f * s2ab);
    const float Cv = -0.5f * s3 + (1.f / 3.f) * fmaf(s1a, s2bc, s2ab * s1c)
                     - 0.25f * s1a * s1b * s1c;

    const float* v3p = s3p + (b * 16 + c) * 16;
    const float* v2p = s2p + c * 16;
#pragma unroll
    for (int d0 = 0; d0 < 16; d0 += 4) {
        const float4 v3 = *(const float4*)(v3p + d0);
        const float4 v2 = *(const float4*)(v2p + d0);
        const float4 v1 = *(const float4*)(s1p + d0);
        s4v[d0 + 0] = fmaf(A, v3.x, s4v[d0 + 0]) + fmaf(Bv, v2.x, Cv * v1.x);
        s4v[d0 + 1] = fmaf(A, v3.y, s4v[d0 + 1]) + fmaf(Bv, v2.y, Cv * v1.y);
        s4v[d0 + 2] = fmaf(A, v3.z, s4v[d0 + 2]) + fmaf(Bv, v2.z, Cv * v1.z);
        s4v[d0 + 3] = fmaf(A, v3.w, s4v[d0 + 3]) + fmaf(Bv, v2.w, Cv * v1.w);
    }

    float* outj = out + (size_t)j * OUTB;
    store_l4(outj + OFF_L4 + a * 4096, s4v, ls, tid);

    const float r3 = s3 - 0.5f * fmaf(s1a, s2bc, s2ab * s1c)
                     + (1.f / 3.f) * s1a * s1b * s1c;
    outj[OFF_L3 + a * 256 + tid] = r3;
    if (tid < 16) outj[OFF_L2 + a * 16 + tid] = fmaf(-0.5f * s1a, s1p[tid], s2p[a * 16 + tid]);
    if (tid == 0) outj[a] = s1a;
}

// ---------------- fallback path (3 kernels) ----------------
__global__ __launch_bounds__(256) void k_dx(const float* __restrict__ path,
                                            float* __restrict__ dx1,
                                            float* __restrict__ dxt) {
    const int j = blockIdx.x;
    const int tid = threadIdx.x;
    __shared__ float L[NT * NC];
    const float* pj = path + (size_t)j * NT * NC;
#pragma unroll
    for (int k = 0; k < 4; ++k) {
        const int f = tid + k * 256;
        *(float4*)&L[f * 4] = *(const float4*)&pj[f * 4];
    }
    __syncthreads();
    float* d1 = dx1 + (size_t)j * NT * NC;
    for (int f = tid; f < NT * NC; f += 256)
        d1[f] = (f < NSTEP * NC) ? (L[f + NC] - L[f]) : 0.f;
    float* dt = dxt + (size_t)j * NC * NT;
#pragma unroll
    for (int k = 0; k < NC; ++k)
        dt[k * 256 + tid] = (tid < NSTEP) ? (L[(tid + 1) * NC + k] - L[tid * NC + k]) : 0.f;
}

__global__ __launch_bounds__(256, 4) void k_scan2(const float* __restrict__ dx1,
                                                  const float* __restrict__ dxt,
                                                  float* __restrict__ out,
                                                  float* __restrict__ sig) {
    const int bid = blockIdx.x;
    const int j = bid >> 4;
    const int a = bid & 15;
    const int tid = threadIdx.x;
    const int b = tid >> 4;
    const int c = tid & 15;

    float s4v[16];
#pragma unroll
    for (int d = 0; d < 16; ++d) s4v[d] = 0.f;
    float s3 = 0.f, s2ab = 0.f, s1a = 0.f;

    const float* row0 = dx1 + (size_t)j * NT * NC;
    const float4* ra4 = (const float4*)(dxt + ((size_t)j * NC + a) * NT);
    const float4* rb4 = (const float4*)(dxt + ((size_t)j * NC + b) * NT);
    const float4* rc4 = (const float4*)(dxt + ((size_t)j * NC + c) * NT);
    scan_core(row0, ra4, rb4, rc4, s4v, s3, s2ab, s1a);

    __shared__ float ls[2176];
    store_l4(out + (size_t)j * OUTB + OFF_L4 + a * 4096, s4v, ls, tid);

    float* sg = sig + (size_t)j * SIG123;
    sg[OFF_L3 + (a * 16 + b) * 16 + c] = s3;
    if (c == 0) sg[OFF_L2 + a * 16 + b] = s2ab;
    if (tid == 0) sg[a] = s1a;
}

__global__ __launch_bounds__(256) void k_log(const float* __restrict__ sig,
                                             float* __restrict__ out) {
    const int bid = blockIdx.x;
    const int j = bid >> 4;
    const int a = bid & 15;
    const int tid = threadIdx.x;

    const float* sg = sig + (size_t)j * SIG123;
    const float* s1p = sg;
    const float* s2p = sg + OFF_L2;
    const float* s3p = sg + OFF_L3;

    const float s1a = s1p[a];
    float* outj = out + (size_t)j * OUTB;
    float* o4 = outj + OFF_L4 + a * 4096;
    const float A = -0.5f * s1a;

#pragma unroll
    for (int k = 0; k < 4; ++k) {
        const int f = tid + k * 256;
        const int m0 = f * 4;
        const int b = m0 >> 8;
        const int c = (m0 >> 4) & 15;
        const float s1b = s1p[b], s1c = s1p[c];
        const float s2ab = s2p[a * 16 + b];
        const float s2bc = s2p[b * 16 + c];
        const float s3abc = s3p[(a * 16 + b) * 16 + c];
        const float Bv = fmaf((1.f / 3.f) * s1a, s1b, -0.5f * s2ab);
        const float Cv = -0.5f * s3abc + (1.f / 3.f) * fmaf(s1a, s2bc, s2ab * s1c)
                         - 0.25f * s1a * s1b * s1c;
        const float4 v4 = *(const float4*)(o4 + m0);
        const float4 v3 = *(const float4*)(s3p + m0);
        const float4 v2 = *(const float4*)(s2p + (m0 & 255));
        const float4 v1 = *(const float4*)(s1p + (m0 & 15));
        float4 rr;
        rr.x = fmaf(A, v3.x, v4.x) + fmaf(Bv, v2.x, Cv * v1.x);
        rr.y = fmaf(A, v3.y, v4.y) + fmaf(Bv, v2.y, Cv * v1.y);
        rr.z = fmaf(A, v3.z, v4.z) + fmaf(Bv, v2.z, Cv * v1.z);
        rr.w = fmaf(A, v3.w, v4.w) + fmaf(Bv, v2.w, Cv * v1.w);
        *(float4*)(o4 + m0) = rr;
    }
    {
        const int b = tid >> 4, c = tid & 15;
        const float s1b = s1p[b], s1c = s1p[c];
        const float s2ab = s2p[a * 16 + b];
        const float s2bc = s2p[b * 16 + c];
        const float s3abc = s3p[(a * 16 + b) * 16 + c];
        outj[OFF_L3 + a * 256 + tid] = s3abc - 0.5f * fmaf(s1a, s2bc, s2ab * s1c)
                                       + (1.f / 3.f) * s1a * s1b * s1c;
    }
    if (tid < 16) outj[OFF_L2 + a * 16 + tid] = fmaf(-0.5f * s1a, s1p[tid], s2p[a * 16 + tid]);
    if (tid == 0) outj[a] = s1a;
}

extern "C" void kernel_launch(void* const* d_in, const int* in_sizes, int n_in,
                              void* d_out, int out_size, void* d_ws, size_t ws_size,
                              hipStream_t stream) {
    const float* path = (const float*)d_in[0];
    float* out = (float*)d_out;
    float* ws = (float*)d_ws;

    void* args[] = {(void*)&path, (void*)&out, (void*)&ws};
    hipError_t rc = hipLaunchCooperativeKernel((const void*)k_fused, dim3(NB * 16),
                                               dim3(256), args, 0, stream);
    if (rc != hipSuccess) {
        float* dx1 = ws;
        float* dxt = ws + DXT_OFF;
        float* sig = ws + SIG_OFF;
        k_dx<<<NB, 256, 0, stream>>>(path, dx1, dxt);
        k_scan2<<<NB * 16, 256, 0, stream>>>(dx1, dxt, out, sig);
        k_log<<<NB * 16, 256, 0, stream>>>(sig, out);
    }
}

// Round 6
// 158.220 us; speedup vs baseline: 4.0439x; 4.0439x over previous
//
#include <hip/hip_runtime.h>

// LogSignature depth-4, C=16, B=64, L=256, fp32 — 3-kernel path.
// out/batch: [lvl1(16) | lvl2(256) | lvl3(4096) | lvl4(65536)] = 69904
// ws (floats): dx1 [j][256][16] (time-major, step 255 zero);
//              dxt [j][16][256] (component-major streams);
//              sig [j][4368]
// Note (R5): cooperative fusion regressed 10x (VALUBusy 6%) and the ~55us
// harness replay overhead is fixed per call, so multi-kernel is fine.

#define NC 16
#define NB 64
#define NSTEP 255
#define NT 256
#define OUTB 69904
#define SIG123 4368
#define OFF_L2 16
#define OFF_L3 272
#define OFF_L4 4368

#define DXT_OFF (NB * NT * NC)            // 262144
#define SIG_OFF (DXT_OFF + NB * NC * NT)  // 524288

// 28 VALU ops/step: 16 s4 FMAs + 12-op replicated scalar chain.
#define CHEN_STEP(DXA, DXB, DXC, Q0, Q1, Q2, Q3)                               \
  do {                                                                         \
    const float Pd = (DXB) * s1a;                                              \
    const float Qd = (DXB) * (DXA);                                            \
    const float pre4 = fmaf(1.f / 6.f, Pd, fmaf(1.f / 24.f, Qd, 0.5f * s2ab)); \
    const float T = fmaf((DXC), pre4, s3);                                     \
    s4v[0] = fmaf((Q0).x, T, s4v[0]);   s4v[1] = fmaf((Q0).y, T, s4v[1]);      \
    s4v[2] = fmaf((Q0).z, T, s4v[2]);   s4v[3] = fmaf((Q0).w, T, s4v[3]);      \
    s4v[4] = fmaf((Q1).x, T, s4v[4]);   s4v[5] = fmaf((Q1).y, T, s4v[5]);      \
    s4v[6] = fmaf((Q1).z, T, s4v[6]);   s4v[7] = fmaf((Q1).w, T, s4v[7]);      \
    s4v[8] = fmaf((Q2).x, T, s4v[8]);   s4v[9] = fmaf((Q2).y, T, s4v[9]);      \
    s4v[10] = fmaf((Q2).z, T, s4v[10]); s4v[11] = fmaf((Q2).w, T, s4v[11]);    \
    s4v[12] = fmaf((Q3).x, T, s4v[12]); s4v[13] = fmaf((Q3).y, T, s4v[13]);    \
    s4v[14] = fmaf((Q3).z, T, s4v[14]); s4v[15] = fmaf((Q3).w, T, s4v[15]);    \
    const float U = fmaf(0.5f, Pd, fmaf(1.f / 6.f, Qd, s2ab));                 \
    s3 = fmaf((DXC), U, s3);                                                   \
    s2ab = fmaf(0.5f, Qd, s2ab + Pd);                                          \
    s1a += (DXA);                                                              \
  } while (0)

#define LOAD_ROWS(Q0, Q1, Q2, Q3, TT)                                 \
  do {                                                                \
    const float4* _rw = (const float4*)(row0 + (((TT)) & 255) * NC);  \
    Q0 = _rw[0]; Q1 = _rw[1]; Q2 = _rw[2]; Q3 = _rw[3];               \
  } while (0)

// Chen scan over 256 steps (step 255 zero). Rows double-buffered at
// distance 2; per-lane streams prefetched one 4-step iter ahead.
__device__ __forceinline__ void scan_core(const float* row0, const float4* ra4,
                                          const float4* rb4, const float4* rc4,
                                          float s4v[16], float& s3, float& s2ab,
                                          float& s1a) {
    float4 p00, p01, p02, p03, p10, p11, p12, p13;
    LOAD_ROWS(p00, p01, p02, p03, 0);
    LOAD_ROWS(p10, p11, p12, p13, 1);
    float4 va = ra4[0], vb = rb4[0], vc = rc4[0];

    for (int it = 0; it < 64; ++it) {
        const int nit = (it + 1) & 63;  // wrap: last prefetch valid mem, unused
        const float4 nva = ra4[nit];
        const float4 nvb = rb4[nit];
        const float4 nvc = rc4[nit];
        const int t = it * 4;
        CHEN_STEP(va.x, vb.x, vc.x, p00, p01, p02, p03);
        LOAD_ROWS(p00, p01, p02, p03, t + 2);
        CHEN_STEP(va.y, vb.y, vc.y, p10, p11, p12, p13);
        LOAD_ROWS(p10, p11, p12, p13, t + 3);
        CHEN_STEP(va.z, vb.z, vc.z, p00, p01, p02, p03);
        LOAD_ROWS(p00, p01, p02, p03, t + 4);
        CHEN_STEP(va.w, vb.w, vc.w, p10, p11, p12, p13);
        LOAD_ROWS(p10, p11, p12, p13, t + 5);
        va = nva; vb = nvb; vc = nvc;
    }
}

// Coalesced level-4 writeout via two-chunk LDS transpose (stride 17 -> at
// most 2-way bank aliasing, which is free). ls holds 2176 floats.
__device__ __forceinline__ void store_l4(float* o4, const float v[16],
                                         float* ls, int tid) {
#pragma unroll
    for (int r = 0; r < 2; ++r) {
        __syncthreads();
        if ((tid >> 7) == r) {
            const int row = tid & 127;
#pragma unroll
            for (int d = 0; d < 16; ++d) ls[row * 17 + d] = v[d];
        }
        __syncthreads();
#pragma unroll
        for (int k = 0; k < 8; ++k) {
            const int el = tid + k * 256;
            o4[r * 2048 + el] = ls[(el >> 4) * 17 + (el & 15)];
        }
    }
}

__global__ __launch_bounds__(256) void k_dx(const float* __restrict__ path,
                                            float* __restrict__ dx1,
                                            float* __restrict__ dxt) {
    const int j = blockIdx.x;
    const int tid = threadIdx.x;
    __shared__ float L[NT * NC];
    const float* pj = path + (size_t)j * NT * NC;
#pragma unroll
    for (int k = 0; k < 4; ++k) {
        const int f = tid + k * 256;
        *(float4*)&L[f * 4] = *(const float4*)&pj[f * 4];
    }
    __syncthreads();
    float* d1 = dx1 + (size_t)j * NT * NC;
    for (int f = tid; f < NT * NC; f += 256)
        d1[f] = (f < NSTEP * NC) ? (L[f + NC] - L[f]) : 0.f;
    float* dt = dxt + (size_t)j * NC * NT;
#pragma unroll
    for (int k = 0; k < NC; ++k)
        dt[k * 256 + tid] = (tid < NSTEP) ? (L[(tid + 1) * NC + k] - L[tid * NC + k]) : 0.f;
}

__global__ __launch_bounds__(256, 4) void k_scan2(const float* __restrict__ dx1,
                                                  const float* __restrict__ dxt,
                                                  float* __restrict__ out,
                                                  float* __restrict__ sig) {
    const int bid = blockIdx.x;
    const int j = bid >> 4;
    const int a = bid & 15;
    const int tid = threadIdx.x;
    const int b = tid >> 4;
    const int c = tid & 15;

    float s4v[16];
#pragma unroll
    for (int d = 0; d < 16; ++d) s4v[d] = 0.f;
    float s3 = 0.f, s2ab = 0.f, s1a = 0.f;

    const float* row0 = dx1 + (size_t)j * NT * NC;
    const float4* ra4 = (const float4*)(dxt + ((size_t)j * NC + a) * NT);
    const float4* rb4 = (const float4*)(dxt + ((size_t)j * NC + b) * NT);
    const float4* rc4 = (const float4*)(dxt + ((size_t)j * NC + c) * NT);
    scan_core(row0, ra4, rb4, rc4, s4v, s3, s2ab, s1a);

    __shared__ float ls[2176];
    store_l4(out + (size_t)j * OUTB + OFF_L4 + a * 4096, s4v, ls, tid);

    float* sg = sig + (size_t)j * SIG123;
    sg[OFF_L3 + (a * 16 + b) * 16 + c] = s3;
    if (c == 0) sg[OFF_L2 + a * 16 + b] = s2ab;
    if (tid == 0) sg[a] = s1a;
}

__global__ __launch_bounds__(256) void k_log(const float* __restrict__ sig,
                                             float* __restrict__ out) {
    const int bid = blockIdx.x;
    const int j = bid >> 4;
    const int a = bid & 15;
    const int tid = threadIdx.x;

    const float* sg = sig + (size_t)j * SIG123;
    const float* s1p = sg;
    const float* s2p = sg + OFF_L2;
    const float* s3p = sg + OFF_L3;

    const float s1a = s1p[a];
    float* outj = out + (size_t)j * OUTB;
    float* o4 = outj + OFF_L4 + a * 4096;
    const float A = -0.5f * s1a;

#pragma unroll
    for (int k = 0; k < 4; ++k) {
        const int f = tid + k * 256;
        const int m0 = f * 4;
        const int b = m0 >> 8;
        const int c = (m0 >> 4) & 15;
        const float s1b = s1p[b], s1c = s1p[c];
        const float s2ab = s2p[a * 16 + b];
        const float s2bc = s2p[b * 16 + c];
        const float s3abc = s3p[(a * 16 + b) * 16 + c];
        const float Bv = fmaf((1.f / 3.f) * s1a, s1b, -0.5f * s2ab);
        const float Cv = -0.5f * s3abc + (1.f / 3.f) * fmaf(s1a, s2bc, s2ab * s1c)
                         - 0.25f * s1a * s1b * s1c;
        const float4 v4 = *(const float4*)(o4 + m0);
        const float4 v3 = *(const float4*)(s3p + m0);
        const float4 v2 = *(const float4*)(s2p + (m0 & 255));
        const float4 v1 = *(const float4*)(s1p + (m0 & 15));
        float4 rr;
        rr.x = fmaf(A, v3.x, v4.x) + fmaf(Bv, v2.x, Cv * v1.x);
        rr.y = fmaf(A, v3.y, v4.y) + fmaf(Bv, v2.y, Cv * v1.y);
        rr.z = fmaf(A, v3.z, v4.z) + fmaf(Bv, v2.z, Cv * v1.z);
        rr.w = fmaf(A, v3.w, v4.w) + fmaf(Bv, v2.w, Cv * v1.w);
        *(float4*)(o4 + m0) = rr;
    }
    {
        const int b = tid >> 4, c = tid & 15;
        const float s1b = s1p[b], s1c = s1p[c];
        const float s2ab = s2p[a * 16 + b];
        const float s2bc = s2p[b * 16 + c];
        const float s3abc = s3p[(a * 16 + b) * 16 + c];
        outj[OFF_L3 + a * 256 + tid] = s3abc - 0.5f * fmaf(s1a, s2bc, s2ab * s1c)
                                       + (1.f / 3.f) * s1a * s1b * s1c;
    }
    if (tid < 16) outj[OFF_L2 + a * 16 + tid] = fmaf(-0.5f * s1a, s1p[tid], s2p[a * 16 + tid]);
    if (tid == 0) outj[a] = s1a;
}

extern "C" void kernel_launch(void* const* d_in, const int* in_sizes, int n_in,
                              void* d_out, int out_size, void* d_ws, size_t ws_size,
                              hipStream_t stream) {
    const float* path = (const float*)d_in[0];
    float* out = (float*)d_out;
    float* ws = (float*)d_ws;
    float* dx1 = ws;
    float* dxt = ws + DXT_OFF;
    float* sig = ws + SIG_OFF;

    k_dx<<<NB, 256, 0, stream>>>(path, dx1, dxt);
    k_scan2<<<NB * 16, 256, 0, stream>>>(dx1, dxt, out, sig);
    k_log<<<NB * 16, 256, 0, stream>>>(sig, out);
}

// Round 7
// 125.368 us; speedup vs baseline: 5.1036x; 1.2620x over previous
//
#include <hip/hip_runtime.h>

// LogSignature depth-4, C=16, B=64, L=256, fp32 — 3-kernel path.
// out/batch: [lvl1(16) | lvl2(256) | lvl3(4096) | lvl4(65536)] = 69904
// ws (floats): dx1 [j][256][16] (time-major, step 255 zero);
//              dxt [j][16][256] (component-major streams);
//              sig [j][4368]
// R5: coop fusion = 10x regression (grid-sync stalls); ~55us harness replay
//     overhead is fixed per call -> multi-kernel is fine.
// R6: manual rotating double-buffer regressed (masked indices broke
//     immediate-offset batching). Keep compiler-scheduled batch loads.

#define NC 16
#define NB 64
#define NSTEP 255
#define NT 256
#define OUTB 69904
#define SIG123 4368
#define OFF_L2 16
#define OFF_L3 272
#define OFF_L4 4368

#define DXT_OFF (NB * NT * NC)            // 262144
#define SIG_OFF (DXT_OFF + NB * NC * NT)  // 524288

// 28 VALU ops/step: 16 s4 FMAs + 12-op replicated scalar chain.
// Consumes float4 components directly (no dv[16] mov-copy).
#define CHEN_STEP(DXA, DXB, DXC, Q0, Q1, Q2, Q3)                               \
  do {                                                                         \
    const float Pd = (DXB) * s1a;                                              \
    const float Qd = (DXB) * (DXA);                                            \
    const float pre4 = fmaf(1.f / 6.f, Pd, fmaf(1.f / 24.f, Qd, 0.5f * s2ab)); \
    const float T = fmaf((DXC), pre4, s3);                                     \
    s4v[0] = fmaf((Q0).x, T, s4v[0]);   s4v[1] = fmaf((Q0).y, T, s4v[1]);      \
    s4v[2] = fmaf((Q0).z, T, s4v[2]);   s4v[3] = fmaf((Q0).w, T, s4v[3]);      \
    s4v[4] = fmaf((Q1).x, T, s4v[4]);   s4v[5] = fmaf((Q1).y, T, s4v[5]);      \
    s4v[6] = fmaf((Q1).z, T, s4v[6]);   s4v[7] = fmaf((Q1).w, T, s4v[7]);      \
    s4v[8] = fmaf((Q2).x, T, s4v[8]);   s4v[9] = fmaf((Q2).y, T, s4v[9]);      \
    s4v[10] = fmaf((Q2).z, T, s4v[10]); s4v[11] = fmaf((Q2).w, T, s4v[11]);    \
    s4v[12] = fmaf((Q3).x, T, s4v[12]); s4v[13] = fmaf((Q3).y, T, s4v[13]);    \
    s4v[14] = fmaf((Q3).z, T, s4v[14]); s4v[15] = fmaf((Q3).w, T, s4v[15]);    \
    const float U = fmaf(0.5f, Pd, fmaf(1.f / 6.f, Qd, s2ab));                 \
    s3 = fmaf((DXC), U, s3);                                                   \
    s2ab = fmaf(0.5f, Qd, s2ab + Pd);                                          \
    s1a += (DXA);                                                              \
  } while (0)

// 8 steps per body: all addresses are immediate offsets off per-iter bases;
// the compiler hoists the 38 loads and inserts fine-grained vmcnt waits.
__device__ __forceinline__ void scan_core(const float* row0, const float4* ra4,
                                          const float4* rb4, const float4* rc4,
                                          float s4v[16], float& s3, float& s2ab,
                                          float& s1a) {
    for (int it = 0; it < 32; ++it) {
        const float4* rw = (const float4*)(row0 + it * 128);  // 8 rows (32 f4)
        const float4 va0 = ra4[2 * it], va1 = ra4[2 * it + 1];
        const float4 vb0 = rb4[2 * it], vb1 = rb4[2 * it + 1];
        const float4 vc0 = rc4[2 * it], vc1 = rc4[2 * it + 1];

        CHEN_STEP(va0.x, vb0.x, vc0.x, rw[0], rw[1], rw[2], rw[3]);
        CHEN_STEP(va0.y, vb0.y, vc0.y, rw[4], rw[5], rw[6], rw[7]);
        CHEN_STEP(va0.z, vb0.z, vc0.z, rw[8], rw[9], rw[10], rw[11]);
        CHEN_STEP(va0.w, vb0.w, vc0.w, rw[12], rw[13], rw[14], rw[15]);
        CHEN_STEP(va1.x, vb1.x, vc1.x, rw[16], rw[17], rw[18], rw[19]);
        CHEN_STEP(va1.y, vb1.y, vc1.y, rw[20], rw[21], rw[22], rw[23]);
        CHEN_STEP(va1.z, vb1.z, vc1.z, rw[24], rw[25], rw[26], rw[27]);
        CHEN_STEP(va1.w, vb1.w, vc1.w, rw[28], rw[29], rw[30], rw[31]);
    }
}

// Coalesced level-4 writeout via two-chunk LDS transpose (stride 17 -> at
// most 2-way bank aliasing, which is free). ls holds 2176 floats.
__device__ __forceinline__ void store_l4(float* o4, const float v[16],
                                         float* ls, int tid) {
#pragma unroll
    for (int r = 0; r < 2; ++r) {
        __syncthreads();
        if ((tid >> 7) == r) {
            const int row = tid & 127;
#pragma unroll
            for (int d = 0; d < 16; ++d) ls[row * 17 + d] = v[d];
        }
        __syncthreads();
#pragma unroll
        for (int k = 0; k < 8; ++k) {
            const int el = tid + k * 256;
            o4[r * 2048 + el] = ls[(el >> 4) * 17 + (el & 15)];
        }
    }
}

__global__ __launch_bounds__(256) void k_dx(const float* __restrict__ path,
                                            float* __restrict__ dx1,
                                            float* __restrict__ dxt) {
    const int j = blockIdx.x;
    const int tid = threadIdx.x;
    __shared__ float L[NT * NC];
    const float* pj = path + (size_t)j * NT * NC;
#pragma unroll
    for (int k = 0; k < 4; ++k) {
        const int f = tid + k * 256;
        *(float4*)&L[f * 4] = *(const float4*)&pj[f * 4];
    }
    __syncthreads();
    float* d1 = dx1 + (size_t)j * NT * NC;
    for (int f = tid; f < NT * NC; f += 256)
        d1[f] = (f < NSTEP * NC) ? (L[f + NC] - L[f]) : 0.f;
    float* dt = dxt + (size_t)j * NC * NT;
#pragma unroll
    for (int k = 0; k < NC; ++k)
        dt[k * 256 + tid] = (tid < NSTEP) ? (L[(tid + 1) * NC + k] - L[tid * NC + k]) : 0.f;
}

__global__ __launch_bounds__(256, 4) void k_scan2(const float* __restrict__ dx1,
                                                  const float* __restrict__ dxt,
                                                  float* __restrict__ out,
                                                  float* __restrict__ sig) {
    const int bid = blockIdx.x;
    const int j = bid >> 4;
    const int a = bid & 15;
    const int tid = threadIdx.x;
    const int b = tid >> 4;
    const int c = tid & 15;

    float s4v[16];
#pragma unroll
    for (int d = 0; d < 16; ++d) s4v[d] = 0.f;
    float s3 = 0.f, s2ab = 0.f, s1a = 0.f;

    const float* row0 = dx1 + (size_t)j * NT * NC;
    const float4* ra4 = (const float4*)(dxt + ((size_t)j * NC + a) * NT);
    const float4* rb4 = (const float4*)(dxt + ((size_t)j * NC + b) * NT);
    const float4* rc4 = (const float4*)(dxt + ((size_t)j * NC + c) * NT);
    scan_core(row0, ra4, rb4, rc4, s4v, s3, s2ab, s1a);

    __shared__ float ls[2176];
    store_l4(out + (size_t)j * OUTB + OFF_L4 + a * 4096, s4v, ls, tid);

    float* sg = sig + (size_t)j * SIG123;
    sg[OFF_L3 + (a * 16 + b) * 16 + c] = s3;
    if (c == 0) sg[OFF_L2 + a * 16 + b] = s2ab;
    if (tid == 0) sg[a] = s1a;
}

__global__ __launch_bounds__(256) void k_log(const float* __restrict__ sig,
                                             float* __restrict__ out) {
    const int bid = blockIdx.x;
    const int j = bid >> 4;
    const int a = bid & 15;
    const int tid = threadIdx.x;

    const float* sg = sig + (size_t)j * SIG123;
    const float* s1p = sg;
    const float* s2p = sg + OFF_L2;
    const float* s3p = sg + OFF_L3;

    const float s1a = s1p[a];
    float* outj = out + (size_t)j * OUTB;
    float* o4 = outj + OFF_L4 + a * 4096;
    const float A = -0.5f * s1a;

#pragma unroll
    for (int k = 0; k < 4; ++k) {
        const int f = tid + k * 256;
        const int m0 = f * 4;
        const int b = m0 >> 8;
        const int c = (m0 >> 4) & 15;
        const float s1b = s1p[b], s1c = s1p[c];
        const float s2ab = s2p[a * 16 + b];
        const float s2bc = s2p[b * 16 + c];
        const float s3abc = s3p[(a * 16 + b) * 16 + c];
        const float Bv = fmaf((1.f / 3.f) * s1a, s1b, -0.5f * s2ab);
        const float Cv = -0.5f * s3abc + (1.f / 3.f) * fmaf(s1a, s2bc, s2ab * s1c)
                         - 0.25f * s1a * s1b * s1c;
        const float4 v4 = *(const float4*)(o4 + m0);
        const float4 v3 = *(const float4*)(s3p + m0);
        const float4 v2 = *(const float4*)(s2p + (m0 & 255));
        const float4 v1 = *(const float4*)(s1p + (m0 & 15));
        float4 rr;
        rr.x = fmaf(A, v3.x, v4.x) + fmaf(Bv, v2.x, Cv * v1.x);
        rr.y = fmaf(A, v3.y, v4.y) + fmaf(Bv, v2.y, Cv * v1.y);
        rr.z = fmaf(A, v3.z, v4.z) + fmaf(Bv, v2.z, Cv * v1.z);
        rr.w = fmaf(A, v3.w, v4.w) + fmaf(Bv, v2.w, Cv * v1.w);
        *(float4*)(o4 + m0) = rr;
    }
    {
        const int b = tid >> 4, c = tid & 15;
        const float s1b = s1p[b], s1c = s1p[c];
        const float s2ab = s2p[a * 16 + b];
        const float s2bc = s2p[b * 16 + c];
        const float s3abc = s3p[(a * 16 + b) * 16 + c];
        outj[OFF_L3 + a * 256 + tid] = s3abc - 0.5f * fmaf(s1a, s2bc, s2ab * s1c)
                                       + (1.f / 3.f) * s1a * s1b * s1c;
    }
    if (tid < 16) outj[OFF_L2 + a * 16 + tid] = fmaf(-0.5f * s1a, s1p[tid], s2p[a * 16 + tid]);
    if (tid == 0) outj[a] = s1a;
}

extern "C" void kernel_launch(void* const* d_in, const int* in_sizes, int n_in,
                              void* d_out, int out_size, void* d_ws, size_t ws_size,
                              hipStream_t stream) {
    const float* path = (const float*)d_in[0];
    float* out = (float*)d_out;
    float* ws = (float*)d_ws;
    float* dx1 = ws;
    float* dxt = ws + DXT_OFF;
    float* sig = ws + SIG_OFF;

    k_dx<<<NB, 256, 0, stream>>>(path, dx1, dxt);
    k_scan2<<<NB * 16, 256, 0, stream>>>(dx1, dxt, out, sig);
    k_log<<<NB * 16, 256, 0, stream>>>(sig, out);
}